// Round 1
// baseline (1281.017 us; speedup 1.0000x reference)
//
#include <hip/hip_runtime.h>
#include <math.h>

#define BATCH 8
#define N 2048
#define D 128
#define ST 4000

#define BI 32   // i-rows per block in fused kernel
#define TJ 64   // j-tile

// ---------------------------------------------------------------------------
// Kernel 1: per-(b,i) softmax row stats: max_j |W| (diag=0) and 1/sum exp
// ---------------------------------------------------------------------------
__global__ __launch_bounds__(256) void row_stats_kernel(
    const int* __restrict__ stk_ten,
    const float* __restrict__ stk_weight,
    float* __restrict__ rowmax,
    float* __restrict__ rowinv)
{
    const int bi = blockIdx.x;            // 0 .. BATCH*N-1
    const int b  = bi >> 11;              // / N
    const int i  = bi & (N - 1);
    const int t  = threadIdx.x;

    const int* idxb = stk_ten + b * N;
    const int ri = idxb[i];
    const float* wrow = stk_weight + (size_t)ri * ST;

    float w8[8];
    float m = 0.0f;                       // values are >= 0 and diag 0 is included
    #pragma unroll
    for (int k = 0; k < 8; ++k) {
        const int j = t + k * 256;
        const int cj = idxb[j];
        float w = fabsf(wrow[cj]);
        if (j == i) w = 0.0f;
        w8[k] = w;
        m = fmaxf(m, w);
    }

    __shared__ float red[256];
    red[t] = m;
    __syncthreads();
    #pragma unroll
    for (int s = 128; s > 0; s >>= 1) {
        if (t < s) red[t] = fmaxf(red[t], red[t + s]);
        __syncthreads();
    }
    const float mx = red[0];
    __syncthreads();

    float s = 0.0f;
    #pragma unroll
    for (int k = 0; k < 8; ++k) s += __expf(w8[k] - mx);
    red[t] = s;
    __syncthreads();
    #pragma unroll
    for (int st2 = 128; st2 > 0; st2 >>= 1) {
        if (t < st2) red[t] += red[t + st2];
        __syncthreads();
    }
    if (t == 0) {
        rowmax[bi] = mx;
        rowinv[bi] = 1.0f / red[0];
    }
}

// ---------------------------------------------------------------------------
// Kernel 2: fused coefficient-gather + GEMM.
// Block: 256 threads, handles BI=32 output rows x all D=128 cols for one batch.
// Loops over j in tiles of TJ=64: stage x tile in LDS, compute coefficient
// tile c[jl][il] = M * exp(|W|-max)*invsum (0 on the positional diagonal),
// then register-blocked 4x4 FMA.
// ---------------------------------------------------------------------------
__global__ __launch_bounds__(256) void fused_gemm_kernel(
    const float* __restrict__ x,
    const int* __restrict__ stk_ten,
    const float* __restrict__ stk_matrix,
    const float* __restrict__ stk_weight,
    const float* __restrict__ rowmax,
    const float* __restrict__ rowinv,
    float* __restrict__ out)
{
    __shared__ float xs[TJ * D];          // 32 KB, [jl][d]
    __shared__ float cs[TJ * BI];         // 8 KB,  [jl][il]  (transposed!)
    __shared__ int   idx_i[BI];
    __shared__ int   idx_j[TJ];
    __shared__ float rmax_s[BI];
    __shared__ float rinv_s[BI];

    const int t  = threadIdx.x;
    const int b  = blockIdx.x >> 6;       // / (N/BI = 64)
    const int it = blockIdx.x & 63;
    const int i0 = it * BI;

    const int* idxb = stk_ten + b * N;
    if (t < BI) {
        const int gi = i0 + t;
        idx_i[t]  = idxb[gi];
        rmax_s[t] = rowmax[b * N + gi];
        rinv_s[t] = rowinv[b * N + gi];
    }

    float acc[4][4];
    #pragma unroll
    for (int r = 0; r < 4; ++r)
        #pragma unroll
        for (int k = 0; k < 4; ++k) acc[r][k] = 0.0f;

    const int tx  = t & 31;
    const int ty  = t >> 5;
    const int d0  = tx * 4;
    const int il0 = ty * 4;

    const float4* xg = (const float4*)(x + ((size_t)(b * N) << 7)); // x[b,:,:]

    for (int jt = 0; jt < N / TJ; ++jt) {
        const int j0 = jt * TJ;
        __syncthreads();                  // protect xs/cs from previous iter readers
        if (t < TJ) idx_j[t] = idxb[j0 + t];
        // stage x tile: TJ*D/4 = 2048 float4s, 8 per thread, coalesced
        {
            const float4* src = xg + ((size_t)j0 << 5);   // j0 * D/4
            float4* dst = (float4*)xs;
            #pragma unroll
            for (int k = 0; k < (TJ * D / 4) / 256; ++k)
                dst[t + k * 256] = src[t + k * 256];
        }
        __syncthreads();
        // coefficient tile: 2048 coefs, 8 per thread; lane-consecutive writes
        #pragma unroll
        for (int k = 0; k < (TJ * BI) / 256; ++k) {
            const int f  = t + k * 256;
            const int jl = f >> 5;        // / BI
            const int il = f & (BI - 1);
            const int gi = i0 + il;
            const int gj = j0 + jl;
            float c;
            if (gi == gj) {
                c = 0.0f;                 // positional diagonal: M=0
            } else {
                const int ri = idx_i[il];
                const int cj = idx_j[jl];
                const size_t off = (size_t)ri * ST + cj;
                const float w  = fabsf(stk_weight[off]);
                const float mv = stk_matrix[off];
                c = mv * __expf(w - rmax_s[il]) * rinv_s[il];
            }
            cs[f] = c;
        }
        __syncthreads();
        // register-blocked matmul: acc[r][k] += cs[jl][il0+r] * xs[jl][d0+k]
        #pragma unroll 8
        for (int jl = 0; jl < TJ; ++jl) {
            const float4 xv = *(const float4*)(xs + jl * D + d0);
            const float4 cv = *(const float4*)(cs + jl * BI + il0);
            const float cvv[4] = {cv.x, cv.y, cv.z, cv.w};
            const float xvv[4] = {xv.x, xv.y, xv.z, xv.w};
            #pragma unroll
            for (int r = 0; r < 4; ++r)
                #pragma unroll
                for (int k = 0; k < 4; ++k)
                    acc[r][k] = fmaf(cvv[r], xvv[k], acc[r][k]);
        }
    }

    // epilogue: coalesced float4 stores
    #pragma unroll
    for (int r = 0; r < 4; ++r) {
        float4 v;
        v.x = acc[r][0]; v.y = acc[r][1]; v.z = acc[r][2]; v.w = acc[r][3];
        *(float4*)(out + ((size_t)(b * N + i0 + il0 + r) << 7) + d0) = v;
    }
}

extern "C" void kernel_launch(void* const* d_in, const int* in_sizes, int n_in,
                              void* d_out, int out_size, void* d_ws, size_t ws_size,
                              hipStream_t stream) {
    const float* x          = (const float*)d_in[0];
    const int*   stk_ten    = (const int*)d_in[1];
    const float* stk_matrix = (const float*)d_in[2];
    const float* stk_weight = (const float*)d_in[3];
    float* out = (float*)d_out;

    float* rowmax = (float*)d_ws;             // BATCH*N floats
    float* rowinv = rowmax + BATCH * N;       // BATCH*N floats

    row_stats_kernel<<<BATCH * N, 256, 0, stream>>>(stk_ten, stk_weight, rowmax, rowinv);
    fused_gemm_kernel<<<BATCH * (N / BI), 256, 0, stream>>>(
        x, stk_ten, stk_matrix, stk_weight, rowmax, rowinv, out);
}

// Round 2
// 472.824 us; speedup vs baseline: 2.7093x; 2.7093x over previous
//
#include <hip/hip_runtime.h>
#include <math.h>

#define BATCH 8
#define N 2048
#define D 128
#define ST 4000

#define BI 64    // i-rows per block in fused kernel
#define TJ 64    // j-tile
#define NT 512   // threads in fused kernel

// ---------------------------------------------------------------------------
// Kernel 0: per-batch bitonic sort of (val,pos). key = (val<<11)|pos, val<4096.
// Sorting j by gathered column value makes every later gather span ~8 cache
// lines per row instead of ~56 (random columns). The matmul is j-permutation
// invariant as long as x rows are permuted identically (we gather x by spos).
// ---------------------------------------------------------------------------
__global__ __launch_bounds__(256) void sort_kernel(
    const int* __restrict__ stk_ten,
    int* __restrict__ sval,
    int* __restrict__ spos)
{
    __shared__ unsigned keys[N];
    const int b = blockIdx.x;
    const int t = threadIdx.x;
    const int* idxb = stk_ten + b * N;
    for (int j = t; j < N; j += 256)
        keys[j] = ((unsigned)idxb[j] << 11) | (unsigned)j;
    __syncthreads();
    for (int k = 2; k <= N; k <<= 1) {
        for (int jj = k >> 1; jj > 0; jj >>= 1) {
            for (int ix = t; ix < N; ix += 256) {
                const int ixj = ix ^ jj;
                if (ixj > ix) {
                    const unsigned a = keys[ix], c = keys[ixj];
                    const bool up = ((ix & k) == 0);
                    if ((a > c) == up) { keys[ix] = c; keys[ixj] = a; }
                }
            }
            __syncthreads();
        }
    }
    for (int j = t; j < N; j += 256) {
        const unsigned kk = keys[j];
        sval[b * N + j] = (int)(kk >> 11);
        spos[b * N + j] = (int)(kk & 2047u);
    }
}

// ---------------------------------------------------------------------------
// Kernel 1: softmax row stats, one WAVE per (b,i) row, sorted-column gathers.
// ---------------------------------------------------------------------------
__global__ __launch_bounds__(256) void row_stats_kernel(
    const int* __restrict__ stk_ten,
    const float* __restrict__ stk_weight,
    const int* __restrict__ sval,
    const int* __restrict__ spos,
    float* __restrict__ rowmax,
    float* __restrict__ rowinv)
{
    const int t    = threadIdx.x;
    const int wave = t >> 6;
    const int lane = t & 63;
    const int bi   = blockIdx.x * 4 + wave;   // grid = BATCH*N/4
    const int b    = bi >> 11;
    const int i    = bi & (N - 1);

    const int ri = stk_ten[b * N + i];
    const float* wrow = stk_weight + (size_t)ri * ST;
    const int* sv = sval + b * N;
    const int* sp = spos + b * N;

    float w32[32];
    float m = 0.0f;                            // diag w=0 included
    #pragma unroll
    for (int k = 0; k < 32; ++k) {
        const int j = lane + (k << 6);
        float w = fabsf(wrow[sv[j]]);
        if (sp[j] == i) w = 0.0f;
        w32[k] = w;
        m = fmaxf(m, w);
    }
    #pragma unroll
    for (int s = 32; s > 0; s >>= 1) m = fmaxf(m, __shfl_xor(m, s, 64));
    float ssum = 0.0f;
    #pragma unroll
    for (int k = 0; k < 32; ++k) ssum += __expf(w32[k] - m);
    #pragma unroll
    for (int s = 32; s > 0; s >>= 1) ssum += __shfl_xor(ssum, s, 64);
    if (lane == 0) {
        rowmax[bi] = m;
        rowinv[bi] = 1.0f / ssum;
    }
}

// ---------------------------------------------------------------------------
// Kernel 2: fused coefficient-gather + GEMM, sorted-j order.
// Block: 512 threads, BI=64 output rows x D=128 cols, one batch.
// Per j-tile: stage 64 gathered x rows (512B contiguous each), gather
// coefficient tile with jl-fastest lanes (64 lanes = 64 sorted adjacent
// columns of ONE matrix row -> ~9 transactions), FMA 4x4 register tile.
// ---------------------------------------------------------------------------
__global__ __launch_bounds__(NT) void fused_gemm_kernel(
    const float* __restrict__ x,
    const int* __restrict__ stk_ten,
    const float* __restrict__ stk_matrix,
    const float* __restrict__ stk_weight,
    const int* __restrict__ sval,
    const int* __restrict__ spos,
    const float* __restrict__ rowmax,
    const float* __restrict__ rowinv,
    float* __restrict__ out)
{
    __shared__ float xs[TJ * D];     // 32 KB, [jl][d]
    __shared__ float cs[BI * TJ];    // 16 KB, [il][jl] (conflict-free writes)
    __shared__ int   sv_s[TJ];
    __shared__ int   sp_s[TJ];
    __shared__ int   ri_s[BI];
    __shared__ float rmax_s[BI];
    __shared__ float rinv_s[BI];

    const int t  = threadIdx.x;
    const int b  = blockIdx.x >> 5;           // / (N/BI = 32)
    const int it = blockIdx.x & 31;
    const int i0 = it * BI;

    if (t < BI) {
        const int gi = i0 + t;
        ri_s[t]   = stk_ten[b * N + gi];
        rmax_s[t] = rowmax[b * N + gi];
        rinv_s[t] = rowinv[b * N + gi];
    }

    float acc[4][4];
    #pragma unroll
    for (int r = 0; r < 4; ++r)
        #pragma unroll
        for (int k = 0; k < 4; ++k) acc[r][k] = 0.0f;

    const int tx  = t & 31;
    const int ty  = t >> 5;         // 0..15
    const int d0  = tx * 4;
    const int il0 = ty * 4;
    const int jlg = t & 63;         // gather column slot (lane-consecutive)
    const int wg  = t >> 6;         // 0..7

    const float4* xg4 = (const float4*)(x + ((size_t)(b * N) << 7));
    const int* svb = sval + b * N;
    const int* spb = spos + b * N;

    for (int jt = 0; jt < N / TJ; ++jt) {
        const int j0 = jt * TJ;
        __syncthreads();                       // previous FMA done with xs/cs
        if (t < TJ) { sv_s[t] = svb[j0 + t]; sp_s[t] = spb[j0 + t]; }
        __syncthreads();

        // stage x rows gathered by original position: 64 rows x 32 float4
        {
            const int c4 = t & 31;
            const int r0 = t >> 5;            // 0..15
            #pragma unroll
            for (int p = 0; p < TJ / 16; ++p) {
                const int jl = r0 + p * 16;
                ((float4*)xs)[jl * 32 + c4] = xg4[(size_t)sp_s[jl] * 32 + c4];
            }
        }

        // coefficient tile: 4096 coefs, 8/thread; lanes sweep sorted columns
        {
            const int cj = sv_s[jlg];
            const int pj = sp_s[jlg];
            #pragma unroll
            for (int k = 0; k < 8; ++k) {
                const int il = wg + (k << 3); // il in 0..63
                const int gi = i0 + il;
                float c;
                if (pj == gi) {
                    c = 0.0f;                 // positional diagonal
                } else {
                    const size_t off = (size_t)ri_s[il] * ST + cj;
                    c = stk_matrix[off] *
                        __expf(fabsf(stk_weight[off]) - rmax_s[il]) * rinv_s[il];
                }
                cs[il * TJ + jlg] = c;
            }
        }
        __syncthreads();

        // register-blocked matmul: acc[r][k] += cs[il0+r][jl] * xs[jl][d0+k]
        #pragma unroll 4
        for (int jl = 0; jl < TJ; ++jl) {
            const float4 xv = *(const float4*)(xs + jl * D + d0);
            float cvv[4];
            #pragma unroll
            for (int r = 0; r < 4; ++r) cvv[r] = cs[(il0 + r) * TJ + jl];
            const float xvv[4] = {xv.x, xv.y, xv.z, xv.w};
            #pragma unroll
            for (int r = 0; r < 4; ++r)
                #pragma unroll
                for (int k = 0; k < 4; ++k)
                    acc[r][k] = fmaf(cvv[r], xvv[k], acc[r][k]);
        }
    }

    #pragma unroll
    for (int r = 0; r < 4; ++r) {
        float4 v;
        v.x = acc[r][0]; v.y = acc[r][1]; v.z = acc[r][2]; v.w = acc[r][3];
        *(float4*)(out + ((size_t)(b * N + i0 + il0 + r) << 7) + d0) = v;
    }
}

extern "C" void kernel_launch(void* const* d_in, const int* in_sizes, int n_in,
                              void* d_out, int out_size, void* d_ws, size_t ws_size,
                              hipStream_t stream) {
    const float* x          = (const float*)d_in[0];
    const int*   stk_ten    = (const int*)d_in[1];
    const float* stk_matrix = (const float*)d_in[2];
    const float* stk_weight = (const float*)d_in[3];
    float* out = (float*)d_out;

    int*   sval   = (int*)d_ws;                       // 64 KB
    int*   spos   = sval + BATCH * N;                 // 64 KB
    float* rowmax = (float*)(spos + BATCH * N);       // 64 KB
    float* rowinv = rowmax + BATCH * N;               // 64 KB

    sort_kernel<<<BATCH, 256, 0, stream>>>(stk_ten, sval, spos);
    row_stats_kernel<<<BATCH * N / 4, 256, 0, stream>>>(
        stk_ten, stk_weight, sval, spos, rowmax, rowinv);
    fused_gemm_kernel<<<BATCH * (N / BI), NT, 0, stream>>>(
        x, stk_ten, stk_matrix, stk_weight, sval, spos, rowmax, rowinv, out);
}

// Round 3
// 397.763 us; speedup vs baseline: 3.2206x; 1.1887x over previous
//
#include <hip/hip_runtime.h>
#include <math.h>

#define BATCH 8
#define N 2048
#define D 128
#define ST 4000

#define BI 32    // i-rows per block in fused kernel
#define TJ 64    // j-tile
#define NT 256   // threads in fused kernel

// ---------------------------------------------------------------------------
// Kernel 0: per-batch bitonic sort of (val,pos). key = (val<<11)|pos.
// Sorted-j gathers span ~9 cache lines per 64 columns instead of ~56.
// Matmul is j-permutation invariant since x rows are permuted identically.
// ---------------------------------------------------------------------------
__global__ __launch_bounds__(1024) void sort_kernel(
    const int* __restrict__ stk_ten,
    int* __restrict__ sval,
    int* __restrict__ spos)
{
    __shared__ unsigned keys[N];
    const int b = blockIdx.x;
    const int t = threadIdx.x;
    const int* idxb = stk_ten + b * N;
    for (int j = t; j < N; j += 1024)
        keys[j] = ((unsigned)idxb[j] << 11) | (unsigned)j;
    __syncthreads();
    for (int k = 2; k <= N; k <<= 1) {
        for (int jj = k >> 1; jj > 0; jj >>= 1) {
            for (int ix = t; ix < N; ix += 1024) {
                const int ixj = ix ^ jj;
                if (ixj > ix) {
                    const unsigned a = keys[ix], c = keys[ixj];
                    const bool up = ((ix & k) == 0);
                    if ((a > c) == up) { keys[ix] = c; keys[ixj] = a; }
                }
            }
            __syncthreads();
        }
    }
    for (int j = t; j < N; j += 1024) {
        const unsigned kk = keys[j];
        sval[b * N + j] = (int)(kk >> 11);
        spos[b * N + j] = (int)(kk & 2047u);
    }
}

// ---------------------------------------------------------------------------
// Kernel 1: softmax row stats, one WAVE per (b,i) row, sorted-column gathers.
// ---------------------------------------------------------------------------
__global__ __launch_bounds__(256) void row_stats_kernel(
    const int* __restrict__ stk_ten,
    const float* __restrict__ stk_weight,
    const int* __restrict__ sval,
    const int* __restrict__ spos,
    float* __restrict__ rowmax,
    float* __restrict__ rowinv)
{
    const int t    = threadIdx.x;
    const int wave = t >> 6;
    const int lane = t & 63;
    const int bi   = blockIdx.x * 4 + wave;   // grid = BATCH*N/4
    const int b    = bi >> 11;
    const int i    = bi & (N - 1);

    const int ri = stk_ten[b * N + i];
    const float* wrow = stk_weight + (size_t)ri * ST;
    const int* sv = sval + b * N;
    const int* sp = spos + b * N;

    float w32[32];
    float m = 0.0f;                            // diag w=0 included
    #pragma unroll
    for (int k = 0; k < 32; ++k) {
        const int j = lane + (k << 6);
        float w = fabsf(wrow[sv[j]]);
        if (sp[j] == i) w = 0.0f;
        w32[k] = w;
        m = fmaxf(m, w);
    }
    #pragma unroll
    for (int s = 32; s > 0; s >>= 1) m = fmaxf(m, __shfl_xor(m, s, 64));
    float ssum = 0.0f;
    #pragma unroll
    for (int k = 0; k < 32; ++k) ssum += __expf(w32[k] - m);
    #pragma unroll
    for (int s = 32; s > 0; s >>= 1) ssum += __shfl_xor(ssum, s, 64);
    if (lane == 0) {
        rowmax[bi] = m;
        rowinv[bi] = 1.0f / ssum;
    }
}

// ---------------------------------------------------------------------------
// Kernel 2: fused coefficient-gather + GEMM, sorted-j order.
// Block: 256 threads, BI=32 output rows x D=128 cols; grid 512 -> 3 blocks/CU
// so gather (latency) and FMA (VALU) phases of different blocks overlap.
// Inner loop chunks jl by 4: cs read as b128 (broadcast), xs as b128 ->
// 8 ds_read_b128 per 64 FMA -> VALU-bound.
// ---------------------------------------------------------------------------
__global__ __launch_bounds__(NT, 3) void fused_gemm_kernel(
    const float* __restrict__ x,
    const int* __restrict__ stk_ten,
    const float* __restrict__ stk_matrix,
    const float* __restrict__ stk_weight,
    const int* __restrict__ sval,
    const int* __restrict__ spos,
    const float* __restrict__ rowmax,
    const float* __restrict__ rowinv,
    float* __restrict__ out)
{
    __shared__ float xs[TJ * D];     // 32 KB, [jl][d]
    __shared__ float cs[BI * TJ];    // 8 KB,  [il][jl]
    __shared__ int   sv_s[TJ];
    __shared__ int   sp_s[TJ];
    __shared__ int   ri_s[BI];
    __shared__ float rmax_s[BI];
    __shared__ float rinv_s[BI];

    const int t  = threadIdx.x;
    const int b  = blockIdx.x >> 6;           // / (N/BI = 64)
    const int it = blockIdx.x & 63;
    const int i0 = it * BI;

    if (t < BI) {
        const int gi = i0 + t;
        ri_s[t]   = stk_ten[b * N + gi];
        rmax_s[t] = rowmax[b * N + gi];
        rinv_s[t] = rowinv[b * N + gi];
    }

    float acc[4][4];
    #pragma unroll
    for (int r = 0; r < 4; ++r)
        #pragma unroll
        for (int k = 0; k < 4; ++k) acc[r][k] = 0.0f;

    const int tx  = t & 31;
    const int ty  = t >> 5;         // 0..7
    const int d0  = tx * 4;
    const int il0 = ty * 4;
    const int jlg = t & 63;         // gather column slot (lane-consecutive)
    const int wg  = t >> 6;         // 0..3

    const float4* xg4 = (const float4*)(x + ((size_t)(b * N) << 7));
    const int* svb = sval + b * N;
    const int* spb = spos + b * N;

    for (int jt = 0; jt < N / TJ; ++jt) {
        const int j0 = jt * TJ;
        __syncthreads();                       // previous FMA done with xs/cs
        if (t < TJ) { sv_s[t] = svb[j0 + t]; sp_s[t] = spb[j0 + t]; }
        __syncthreads();

        // stage x rows gathered by original position: 64 rows x 32 float4
        {
            const int c4 = t & 31;
            const int r0 = t >> 5;            // 0..7
            #pragma unroll
            for (int p = 0; p < TJ / 8; ++p) {
                const int jl = r0 + p * 8;
                ((float4*)xs)[jl * 32 + c4] = xg4[(size_t)sp_s[jl] * 32 + c4];
            }
        }

        // coefficient tile: 2048 coefs, 8/thread; lanes sweep sorted columns
        {
            const int cj = sv_s[jlg];
            const int pj = sp_s[jlg];
            #pragma unroll
            for (int k = 0; k < 8; ++k) {
                const int il = wg + (k << 2); // il in 0..31
                const int gi = i0 + il;
                float c;
                if (pj == gi) {
                    c = 0.0f;                 // positional diagonal
                } else {
                    const size_t off = (size_t)ri_s[il] * ST + cj;
                    c = stk_matrix[off] *
                        __expf(fabsf(stk_weight[off]) - rmax_s[il]) * rinv_s[il];
                }
                cs[il * TJ + jlg] = c;
            }
        }
        __syncthreads();

        // register-blocked matmul, jl chunked by 4:
        // acc[r][k] += cs[il0+r][jc+q] * xs[jc+q][d0+k]
        #pragma unroll 2
        for (int jc = 0; jc < TJ; jc += 4) {
            float4 xv[4], cv[4];
            #pragma unroll
            for (int q = 0; q < 4; ++q)
                xv[q] = *(const float4*)(xs + (jc + q) * D + d0);
            #pragma unroll
            for (int r = 0; r < 4; ++r)
                cv[r] = *(const float4*)(cs + (il0 + r) * TJ + jc);
            #pragma unroll
            for (int q = 0; q < 4; ++q) {
                const float xq[4] = {xv[q].x, xv[q].y, xv[q].z, xv[q].w};
                const float cq[4] = {((const float*)&cv[0])[q],
                                     ((const float*)&cv[1])[q],
                                     ((const float*)&cv[2])[q],
                                     ((const float*)&cv[3])[q]};
                #pragma unroll
                for (int r = 0; r < 4; ++r)
                    #pragma unroll
                    for (int k = 0; k < 4; ++k)
                        acc[r][k] = fmaf(cq[r], xq[k], acc[r][k]);
            }
        }
    }

    #pragma unroll
    for (int r = 0; r < 4; ++r) {
        float4 v;
        v.x = acc[r][0]; v.y = acc[r][1]; v.z = acc[r][2]; v.w = acc[r][3];
        *(float4*)(out + ((size_t)(b * N + i0 + il0 + r) << 7) + d0) = v;
    }
}

extern "C" void kernel_launch(void* const* d_in, const int* in_sizes, int n_in,
                              void* d_out, int out_size, void* d_ws, size_t ws_size,
                              hipStream_t stream) {
    const float* x          = (const float*)d_in[0];
    const int*   stk_ten    = (const int*)d_in[1];
    const float* stk_matrix = (const float*)d_in[2];
    const float* stk_weight = (const float*)d_in[3];
    float* out = (float*)d_out;

    int*   sval   = (int*)d_ws;                       // 64 KB
    int*   spos   = sval + BATCH * N;                 // 64 KB
    float* rowmax = (float*)(spos + BATCH * N);       // 64 KB
    float* rowinv = rowmax + BATCH * N;               // 64 KB

    sort_kernel<<<BATCH, 1024, 0, stream>>>(stk_ten, sval, spos);
    row_stats_kernel<<<BATCH * N / 4, 256, 0, stream>>>(
        stk_ten, stk_weight, sval, spos, rowmax, rowinv);
    fused_gemm_kernel<<<BATCH * (N / BI), NT, 0, stream>>>(
        x, stk_ten, stk_matrix, stk_weight, sval, spos, rowmax, rowinv, out);
}